// Round 1
// baseline (12555.018 us; speedup 1.0000x reference)
//
#include <hip/hip_runtime.h>
#include <hip/hip_bf16.h>
#include <math.h>

#define DIMV   768
#define BATCH  64
#define KEEPT  49
#define MTOK   (BATCH*KEEPT)   // 3136
#define NHEADS 12
#define DHEAD  64
#define FFV    3072
#define NDEPTH 12

// ---------------------------------------------------------------------------
// gather kept-patch pixels into a (MTOK x 768) matrix (row = b*49+t, col = ky*48+kx*3+c)
// class-token rows (mask==0, can't actually occur) are zeroed; finish_embed overwrites them.
__global__ __launch_bounds__(256) void gather_patches(
    const float* __restrict__ inp, const int* __restrict__ mask,
    float* __restrict__ apix)
{
  int gid = blockIdx.x * 256 + threadIdx.x;
  if (gid >= MTOK * DIMV) return;
  int r = gid / DIMV, k = gid - r * DIMV;
  int b = r / KEEPT, t = r - b * KEEPT;
  int j = mask[t];
  j = j < 0 ? 0 : (j > 196 ? 196 : j);   // JAX clamps OOB gather indices
  float v = 0.f;
  if (j > 0) {
    int p  = j - 1, py = p / 14, px = p - py * 14;
    int ky = k / 48, rem = k - ky * 48, kx = rem / 3, c = rem - kx * 3;
    v = inp[(((b * 224) + py * 16 + ky) * 224 + px * 16 + kx) * 3 + c];
  }
  apix[gid] = v;
}

// x = (j==0 ? ct : x) + pe[j]
__global__ __launch_bounds__(256) void finish_embed(
    float* __restrict__ x, const float* __restrict__ ct,
    const float* __restrict__ pe, const int* __restrict__ mask)
{
  int gid = blockIdx.x * 256 + threadIdx.x;
  if (gid >= MTOK * DIMV) return;
  int r = gid / DIMV, d = gid - r * DIMV;
  int t = r % KEEPT;
  int j = mask[t];
  j = j < 0 ? 0 : (j > 196 ? 196 : j);
  float base = (j == 0) ? ct[d] : x[gid];
  x[gid] = base + pe[j * DIMV + d];
}

// ---------------------------------------------------------------------------
// row layernorm, eps=1e-9, 256 threads / row (3 elems per thread)
__global__ __launch_bounds__(256) void layernorm_k(
    const float* __restrict__ x, const float* __restrict__ sc,
    const float* __restrict__ bi, float* __restrict__ out)
{
  __shared__ float red[8];
  int r = blockIdx.x;
  const float* xr = x + (size_t)r * DIMV;
  int t = threadIdx.x;
  float v[3];
  float s = 0.f, ss = 0.f;
#pragma unroll
  for (int i = 0; i < 3; i++) {
    float a = xr[t + i * 256];
    v[i] = a; s += a; ss += a * a;
  }
#pragma unroll
  for (int off = 32; off > 0; off >>= 1) {
    s  += __shfl_down(s,  off, 64);
    ss += __shfl_down(ss, off, 64);
  }
  int wave = t >> 6, lane = t & 63;
  if (lane == 0) { red[wave] = s; red[4 + wave] = ss; }
  __syncthreads();
  if (t == 0) {
    float a  = red[0] + red[1] + red[2] + red[3];
    float b2 = red[4] + red[5] + red[6] + red[7];
    float m  = a * (1.f / DIMV);
    float var = b2 * (1.f / DIMV) - m * m;
    red[0] = m;
    red[1] = rsqrtf(var + 1e-9f);
  }
  __syncthreads();
  float m = red[0], rs = red[1];
  float* outr = out + (size_t)r * DIMV;
#pragma unroll
  for (int i = 0; i < 3; i++) {
    int d = t + i * 256;
    outr[d] = (v[i] - m) * rs * sc[d] + bi[d];
  }
}

// ---------------------------------------------------------------------------
// fp32 tiled GEMM: C = A(MxK) * B(KxN) [+ bias] [gelu] [+ Cin]
// 128x128 tile, BK=8, 256 threads, 8x8 per thread. N,K multiples of 128/8; M guarded.
enum { EPI_NONE = 0, EPI_RESID = 1, EPI_BIAS_GELU = 2, EPI_BIAS_RESID = 3 };

template <int EPI>
__global__ __launch_bounds__(256) void gemm_f32(
    const float* __restrict__ A, const float* __restrict__ B,
    const float* __restrict__ Cin, const float* __restrict__ bias,
    float* __restrict__ Cout, int M, int N, int K)
{
  __shared__ float As[8][128];
  __shared__ float Bs[8][128];
  const int tid = threadIdx.x;
  const int bm = blockIdx.y, bn = blockIdx.x;
  const int tx = tid & 15, ty = tid >> 4;
  const int arow = tid >> 1, acol = (tid & 1) * 4;
  const int brow = tid >> 5, bcol = (tid & 31) * 4;

  float acc[8][8];
#pragma unroll
  for (int i = 0; i < 8; i++)
#pragma unroll
    for (int j = 0; j < 8; j++) acc[i][j] = 0.f;

  const int a_grow = min(bm * 128 + arow, M - 1);       // clamp (rows >= M unused)
  const float* Aptr = A + (size_t)a_grow * K + acol;
  const float* Bptr = B + (size_t)brow * N + bn * 128 + bcol;

  for (int k0 = 0; k0 < K; k0 += 8) {
    float4 av = *(const float4*)(Aptr + k0);
    float4 bv = *(const float4*)(Bptr + (size_t)k0 * N);
    __syncthreads();
    As[acol + 0][arow] = av.x;
    As[acol + 1][arow] = av.y;
    As[acol + 2][arow] = av.z;
    As[acol + 3][arow] = av.w;
    *(float4*)&Bs[brow][bcol] = bv;
    __syncthreads();
#pragma unroll
    for (int k = 0; k < 8; k++) {
      float4 a0 = *(const float4*)&As[k][ty * 8];
      float4 a1 = *(const float4*)&As[k][ty * 8 + 4];
      float4 b0 = *(const float4*)&Bs[k][tx * 4];
      float4 b1 = *(const float4*)&Bs[k][tx * 4 + 64];
      float av8[8] = {a0.x, a0.y, a0.z, a0.w, a1.x, a1.y, a1.z, a1.w};
      float bv8[8] = {b0.x, b0.y, b0.z, b0.w, b1.x, b1.y, b1.z, b1.w};
#pragma unroll
      for (int i = 0; i < 8; i++)
#pragma unroll
        for (int j = 0; j < 8; j++)
          acc[i][j] += av8[i] * bv8[j];
    }
  }

#pragma unroll
  for (int i = 0; i < 8; i++) {
    int r = bm * 128 + ty * 8 + i;
    if (r < M) {
#pragma unroll
      for (int g = 0; g < 2; g++) {
        int c = bn * 128 + g * 64 + tx * 4;
        float vals[4];
#pragma unroll
        for (int j = 0; j < 4; j++) vals[j] = acc[i][g * 4 + j];
#pragma unroll
        for (int j = 0; j < 4; j++) {
          float u = vals[j];
          if (EPI == EPI_BIAS_GELU || EPI == EPI_BIAS_RESID) u += bias[c + j];
          if (EPI == EPI_BIAS_GELU) {
            float t3 = u * u * u;
            u = 0.5f * u * (1.f + tanhf(0.7978845608028654f * (u + 0.044715f * t3)));
          }
          if (EPI == EPI_RESID || EPI == EPI_BIAS_RESID) u += Cin[(size_t)r * N + c + j];
          vals[j] = u;
        }
        *(float4*)&Cout[(size_t)r * N + c] =
            make_float4(vals[0], vals[1], vals[2], vals[3]);
      }
    }
  }
}

// ---------------------------------------------------------------------------
// fused attention: one block per (batch, head); 49 tokens, head dim 64.
__global__ __launch_bounds__(64) void attn_k(
    const float* __restrict__ qkv, float* __restrict__ o)
{
  __shared__ float qs[49][65];   // +1 pad: row-indexed-by-lane reads
  __shared__ float ks[49][64];   // broadcast reads, no pad needed
  __shared__ float vs[49][64];
  __shared__ float ssc[49][50];
  int b = blockIdx.x, hh = blockIdx.y;
  int t = threadIdx.x;

  for (int idx = t; idx < 49 * 64; idx += 64) {
    int tok = idx >> 6, d = idx & 63;
    size_t base = (size_t)(b * KEEPT + tok) * (3 * DIMV) + hh * 64 + d;
    qs[tok][d] = qkv[base];
    ks[tok][d] = qkv[base + DIMV];
    vs[tok][d] = qkv[base + 2 * DIMV];
  }
  __syncthreads();

  if (t < KEEPT) {
    float mx = -1e30f;
    for (int j = 0; j < KEEPT; j++) {
      float acc = 0.f;
#pragma unroll
      for (int d = 0; d < 64; d++) acc += qs[t][d] * ks[j][d];
      acc *= 0.125f;             // 1/sqrt(64)
      ssc[t][j] = acc;
      mx = fmaxf(mx, acc);
    }
    float sum = 0.f;
    for (int j = 0; j < KEEPT; j++) {
      float e = __expf(ssc[t][j] - mx);
      ssc[t][j] = e;
      sum += e;
    }
    float inv = 1.f / sum;
    float oa[64];
#pragma unroll
    for (int d = 0; d < 64; d++) oa[d] = 0.f;
    for (int j = 0; j < KEEPT; j++) {
      float w = ssc[t][j] * inv;
#pragma unroll
      for (int d = 0; d < 64; d++) oa[d] += w * vs[j][d];
    }
    float* orow = o + (size_t)(b * KEEPT + t) * DIMV + hh * 64;
#pragma unroll
    for (int d = 0; d < 64; d++) orow[d] = oa[d];
  }
}

// ---------------------------------------------------------------------------
extern "C" void kernel_launch(void* const* d_in, const int* in_sizes, int n_in,
                              void* d_out, int out_size, void* d_ws, size_t ws_size,
                              hipStream_t stream)
{
  (void)in_sizes; (void)n_in; (void)out_size; (void)ws_size;
  const float* inputs = (const float*)d_in[0];
  const float* conv_w = (const float*)d_in[1];
  const float* ct     = (const float*)d_in[2];
  const float* pe     = (const float*)d_in[3];
  const float* ln1_s  = (const float*)d_in[4];
  const float* ln1_b  = (const float*)d_in[5];
  const float* qkv_w  = (const float*)d_in[6];
  const float* proj_w = (const float*)d_in[7];
  const float* ln2_s  = (const float*)d_in[8];
  const float* ln2_b  = (const float*)d_in[9];
  const float* w1     = (const float*)d_in[10];
  const float* b1     = (const float*)d_in[11];
  const float* w2     = (const float*)d_in[12];
  const float* b2     = (const float*)d_in[13];
  const int*   mask   = (const int*)d_in[14];
  float* out = (float*)d_out;

  // workspace layout (fp32): x | h | (qkv -aliased-with- g/apix)
  float* ws  = (float*)d_ws;
  float* x   = ws;
  float* h   = x + (size_t)MTOK * DIMV;
  float* big = h + (size_t)MTOK * DIMV;   // MTOK*3072 floats; holds apix, qkv, g
  float* qkv = big;
  float* g   = big;
  float* apx = big;

  dim3 blk(256);
  const int nelem  = MTOK * DIMV;
  const int nblk   = (nelem + 255) / 256;
  const int mgrid  = (MTOK + 127) / 128;   // 25

  gather_patches<<<nblk, blk, 0, stream>>>(inputs, mask, apx);
  gemm_f32<EPI_NONE><<<dim3(DIMV / 128, mgrid), blk, 0, stream>>>(
      apx, conv_w, nullptr, nullptr, x, MTOK, DIMV, DIMV);
  finish_embed<<<nblk, blk, 0, stream>>>(x, ct, pe, mask);

  for (int l = 0; l < NDEPTH; l++) {
    layernorm_k<<<MTOK, blk, 0, stream>>>(x, ln1_s + l * DIMV, ln1_b + l * DIMV, h);
    gemm_f32<EPI_NONE><<<dim3(3 * DIMV / 128, mgrid), blk, 0, stream>>>(
        h, qkv_w + (size_t)l * DIMV * 3 * DIMV, nullptr, nullptr, qkv,
        MTOK, 3 * DIMV, DIMV);
    attn_k<<<dim3(BATCH, NHEADS), dim3(64), 0, stream>>>(qkv, h);
    gemm_f32<EPI_RESID><<<dim3(DIMV / 128, mgrid), blk, 0, stream>>>(
        h, proj_w + (size_t)l * DIMV * DIMV, x, nullptr, x, MTOK, DIMV, DIMV);
    layernorm_k<<<MTOK, blk, 0, stream>>>(x, ln2_s + l * DIMV, ln2_b + l * DIMV, h);
    gemm_f32<EPI_BIAS_GELU><<<dim3(FFV / 128, mgrid), blk, 0, stream>>>(
        h, w1 + (size_t)l * DIMV * FFV, nullptr, b1 + (size_t)l * FFV, g,
        MTOK, FFV, DIMV);
    float* dst = (l == NDEPTH - 1) ? out : x;
    gemm_f32<EPI_BIAS_RESID><<<dim3(DIMV / 128, mgrid), blk, 0, stream>>>(
        g, w2 + (size_t)l * FFV * DIMV, x, b2 + (size_t)l * DIMV, dst,
        MTOK, DIMV, FFV);
  }
}

// Round 2
// 2730.298 us; speedup vs baseline: 4.5984x; 4.5984x over previous
//
#include <hip/hip_runtime.h>
#include <hip/hip_bf16.h>
#include <math.h>

#define DIMV   768
#define BATCH  64
#define KEEPT  49
#define MTOK   (BATCH*KEEPT)   // 3136
#define NHEADS 12
#define DHEAD  64
#define FFV    3072
#define NDEPTH 12

typedef short short8 __attribute__((ext_vector_type(8)));
typedef float floatx4 __attribute__((ext_vector_type(4)));
typedef unsigned short ushort;

// ---------------------------------------------------------------------------
__device__ __forceinline__ void async_cp16(const void* g, void* l) {
  __builtin_amdgcn_global_load_lds((const __attribute__((address_space(1))) void*)g,
                                   (__attribute__((address_space(3))) void*)l,
                                   16, 0, 0);
}

// ---------------------------------------------------------------------------
// gather kept-patch pixels into (MTOK x 768) bf16 matrix
__global__ __launch_bounds__(256) void gather_patches(
    const float* __restrict__ inp, const int* __restrict__ mask,
    __hip_bfloat16* __restrict__ apix)
{
  int gid = blockIdx.x * 256 + threadIdx.x;
  if (gid >= MTOK * DIMV) return;
  int r = gid / DIMV, k = gid - r * DIMV;
  int b = r / KEEPT, t = r - b * KEEPT;
  int j = mask[t];
  j = j < 0 ? 0 : (j > 196 ? 196 : j);   // JAX clamps OOB gather indices
  float v = 0.f;
  if (j > 0) {
    int p  = j - 1, py = p / 14, px = p - py * 14;
    int ky = k / 48, rem = k - ky * 48, kx = rem / 3, c = rem - kx * 3;
    v = inp[(((b * 224) + py * 16 + ky) * 224 + px * 16 + kx) * 3 + c];
  }
  apix[gid] = __float2bfloat16(v);
}

// x = (j==0 ? ct : x) + pe[j]   (fp32 residual stream)
__global__ __launch_bounds__(256) void finish_embed(
    float* __restrict__ x, const float* __restrict__ ct,
    const float* __restrict__ pe, const int* __restrict__ mask)
{
  int gid = blockIdx.x * 256 + threadIdx.x;
  if (gid >= MTOK * DIMV) return;
  int r = gid / DIMV, d = gid - r * DIMV;
  int t = r % KEEPT;
  int j = mask[t];
  j = j < 0 ? 0 : (j > 196 ? 196 : j);
  float base = (j == 0) ? ct[d] : x[gid];
  x[gid] = base + pe[j * DIMV + d];
}

// ---------------------------------------------------------------------------
// row layernorm fp32 -> bf16, eps=1e-9
__global__ __launch_bounds__(256) void layernorm_k(
    const float* __restrict__ x, const float* __restrict__ sc,
    const float* __restrict__ bi, __hip_bfloat16* __restrict__ out)
{
  __shared__ float red[8];
  int r = blockIdx.x;
  const float* xr = x + (size_t)r * DIMV;
  int t = threadIdx.x;
  float v[3];
  float s = 0.f, ss = 0.f;
#pragma unroll
  for (int i = 0; i < 3; i++) {
    float a = xr[t + i * 256];
    v[i] = a; s += a; ss += a * a;
  }
#pragma unroll
  for (int off = 32; off > 0; off >>= 1) {
    s  += __shfl_down(s,  off, 64);
    ss += __shfl_down(ss, off, 64);
  }
  int wave = t >> 6, lane = t & 63;
  if (lane == 0) { red[wave] = s; red[4 + wave] = ss; }
  __syncthreads();
  if (t == 0) {
    float a  = red[0] + red[1] + red[2] + red[3];
    float b2 = red[4] + red[5] + red[6] + red[7];
    float m  = a * (1.f / DIMV);
    float var = b2 * (1.f / DIMV) - m * m;
    red[0] = m;
    red[1] = rsqrtf(var + 1e-9f);
  }
  __syncthreads();
  float m = red[0], rs = red[1];
  __hip_bfloat16* outr = out + (size_t)r * DIMV;
#pragma unroll
  for (int i = 0; i < 3; i++) {
    int d = t + i * 256;
    outr[d] = __float2bfloat16((v[i] - m) * rs * sc[d] + bi[d]);
  }
}

// ---------------------------------------------------------------------------
// 32x32-tile fp32 -> bf16 transpose helper (dst[c][r] = bf16(src[r][c]))
__device__ __forceinline__ void transpose_tile(
    const float* __restrict__ src, __hip_bfloat16* __restrict__ dst,
    int R, int C, int tr, int tcc)
{
  __shared__ float lds[32][33];
  int x = threadIdx.x & 31, y = threadIdx.x >> 5;
  int r0 = tr * 32, c0 = tcc * 32;
#pragma unroll
  for (int i = 0; i < 4; i++)
    lds[y + 8 * i][x] = src[(size_t)(r0 + y + 8 * i) * C + c0 + x];
  __syncthreads();
#pragma unroll
  for (int i = 0; i < 4; i++)
    dst[(size_t)(c0 + y + 8 * i) * R + r0 + x] = __float2bfloat16(lds[x][y + 8 * i]);
}

__global__ __launch_bounds__(256) void transpose_one(
    const float* __restrict__ src, __hip_bfloat16* __restrict__ dst, int R, int C)
{
  int tc = C >> 5;
  transpose_tile(src, dst, R, C, blockIdx.x / tc, blockIdx.x % tc);
}

// fused per-layer weight convert+transpose.
// tiles: qkv(768x2304)=1728, proj(768x768)=576, w1(768x3072)=2304, w2(3072x768)=2304
#define QKV_TE  ((size_t)2304*768)
#define PROJ_TE ((size_t)768*768)
#define W1_TE   ((size_t)3072*768)
#define W2_TE   ((size_t)768*3072)
#define LSTRIDE (QKV_TE + PROJ_TE + W1_TE + W2_TE)   // 7,077,888 elems

__global__ __launch_bounds__(256) void convert_weights(
    const float* __restrict__ qkv_w, const float* __restrict__ proj_w,
    const float* __restrict__ w1, const float* __restrict__ w2,
    __hip_bfloat16* __restrict__ dstBase, int layer0, size_t dstStride)
{
  int l = layer0 + blockIdx.y;
  __hip_bfloat16* d = dstBase + (size_t)blockIdx.y * dstStride;
  int tile = blockIdx.x;
  const float* src; __hip_bfloat16* dst; int R, C, t0;
  if (tile < 1728)      { src = qkv_w  + (size_t)l*768*2304; dst = d;                          R=768;  C=2304; t0=tile; }
  else if (tile < 2304) { src = proj_w + (size_t)l*768*768;  dst = d + QKV_TE;                 R=768;  C=768;  t0=tile-1728; }
  else if (tile < 4608) { src = w1     + (size_t)l*768*3072; dst = d + QKV_TE+PROJ_TE;         R=768;  C=3072; t0=tile-2304; }
  else                  { src = w2     + (size_t)l*3072*768; dst = d + QKV_TE+PROJ_TE+W1_TE;   R=3072; C=768;  t0=tile-4608; }
  int tc = C >> 5;
  transpose_tile(src, dst, R, C, t0 / tc, t0 % tc);
}

// ---------------------------------------------------------------------------
// bf16 MFMA GEMM: C = A(MxK) * Bt^T  (Bt is N x K row-major, pre-transposed)
// block tile 128 x TN, 4 waves, 16x16x32 MFMA, fp32 accum.
enum { EPI_NONE = 0, EPI_RESID = 1, EPI_BIAS_GELU = 2, EPI_BIAS_RESID = 3 };

template <int TN, int EPI, bool OUT_BF16>
__global__ __launch_bounds__(256) void gemm_mfma(
    const ushort* __restrict__ A, const ushort* __restrict__ Bt,
    const float* __restrict__ Cin, const float* __restrict__ bias,
    void* __restrict__ Cout, int M, int N, int K)
{
  constexpr int AM = (TN == 128) ? 4 : 2;   // A frags / wave (WM = AM*16)
  constexpr int B_LOADS = TN / 64;          // 1KB wave-loads for Bs
  __shared__ ushort As[128 * 32];
  __shared__ ushort Bs[TN * 32];

  const int tid  = threadIdx.x;
  const int wave = tid >> 6, lane = tid & 63;
  const int bm = blockIdx.y, bn = blockIdx.x;

  const int wm0 = (TN == 128) ? (wave & 1) * 64 : wave * 32;
  const int wn0 = (TN == 128) ? (wave >> 1) * 64 : 0;

  floatx4 acc[AM][4];
#pragma unroll
  for (int i = 0; i < AM; i++)
#pragma unroll
    for (int j = 0; j < 4; j++) { floatx4 z = {0.f,0.f,0.f,0.f}; acc[i][j] = z; }

  // staging source pointers: lane -> row (lane>>2), k-chunk (lane&3)*8
  const int lrow = lane >> 2, lchunk = (lane & 3) * 8;
  const ushort* aSrc[2];
  ushort*       aDst[2];
#pragma unroll
  for (int i = 0; i < 2; i++) {
    int row = bm * 128 + (wave * 2 + i) * 16 + lrow;
    row = row < M - 1 ? row : M - 1;
    aSrc[i] = A + (size_t)row * K + lchunk;
    aDst[i] = As + (wave * 2 + i) * 512;      // wave-uniform base (1KB per load)
  }
  const ushort* bSrc[B_LOADS];
  ushort*       bDst[B_LOADS];
#pragma unroll
  for (int i = 0; i < B_LOADS; i++) {
    int row = bn * TN + (wave * B_LOADS + i) * 16 + lrow;
    bSrc[i] = Bt + (size_t)row * K + lchunk;
    bDst[i] = Bs + (wave * B_LOADS + i) * 512;
  }

  for (int k0 = 0; k0 < K; k0 += 32) {
    __syncthreads();
#pragma unroll
    for (int i = 0; i < 2; i++)       async_cp16(aSrc[i] + k0, aDst[i]);
#pragma unroll
    for (int i = 0; i < B_LOADS; i++) async_cp16(bSrc[i] + k0, bDst[i]);
    __syncthreads();

    short8 af[AM], bf[4];
#pragma unroll
    for (int mt = 0; mt < AM; mt++)
      af[mt] = *(const short8*)&As[(wm0 + mt * 16 + (lane & 15)) * 32 + (lane >> 4) * 8];
#pragma unroll
    for (int nt = 0; nt < 4; nt++)
      bf[nt] = *(const short8*)&Bs[(wn0 + nt * 16 + (lane & 15)) * 32 + (lane >> 4) * 8];
#pragma unroll
    for (int mt = 0; mt < AM; mt++)
#pragma unroll
      for (int nt = 0; nt < 4; nt++)
        acc[mt][nt] = __builtin_amdgcn_mfma_f32_16x16x32_bf16(af[mt], bf[nt], acc[mt][nt], 0, 0, 0);
  }

  // epilogue: C row = wm0+mt*16+(lane>>4)*4+r, col = wn0+nt*16+(lane&15)
  const int colb = bn * TN + wn0 + (lane & 15);
  const int rq   = (lane >> 4) * 4;
#pragma unroll
  for (int mt = 0; mt < AM; mt++) {
#pragma unroll
    for (int r = 0; r < 4; r++) {
      int row = bm * 128 + wm0 + mt * 16 + rq + r;
      if (row >= M) continue;
#pragma unroll
      for (int nt = 0; nt < 4; nt++) {
        int col = colb + nt * 16;
        float u = acc[mt][nt][r];
        if (EPI == EPI_BIAS_GELU || EPI == EPI_BIAS_RESID) u += bias[col];
        if (EPI == EPI_BIAS_GELU) {
          float t3 = u * u * u;
          u = 0.5f * u * (1.f + tanhf(0.7978845608028654f * (u + 0.044715f * t3)));
        }
        if (EPI == EPI_RESID || EPI == EPI_BIAS_RESID) u += Cin[(size_t)row * N + col];
        if (OUT_BF16)
          ((__hip_bfloat16*)Cout)[(size_t)row * N + col] = __float2bfloat16(u);
        else
          ((float*)Cout)[(size_t)row * N + col] = u;
      }
    }
  }
}

// ---------------------------------------------------------------------------
// fused attention: one block per (batch, head); 49 tokens, head dim 64. bf16 I/O.
__global__ __launch_bounds__(64) void attn_k(
    const __hip_bfloat16* __restrict__ qkv, __hip_bfloat16* __restrict__ o)
{
  __shared__ float qs[49][65];
  __shared__ float ks[49][64];
  __shared__ float vs[49][64];
  __shared__ float ssc[49][50];
  int b = blockIdx.x, hh = blockIdx.y;
  int t = threadIdx.x;

  for (int idx = t; idx < 49 * 64; idx += 64) {
    int tok = idx >> 6, d = idx & 63;
    size_t base = (size_t)(b * KEEPT + tok) * (3 * DIMV) + hh * 64 + d;
    qs[tok][d] = __bfloat162float(qkv[base]);
    ks[tok][d] = __bfloat162float(qkv[base + DIMV]);
    vs[tok][d] = __bfloat162float(qkv[base + 2 * DIMV]);
  }
  __syncthreads();

  if (t < KEEPT) {
    float mx = -1e30f;
    for (int j = 0; j < KEEPT; j++) {
      float acc = 0.f;
#pragma unroll
      for (int d = 0; d < 64; d++) acc += qs[t][d] * ks[j][d];
      acc *= 0.125f;
      ssc[t][j] = acc;
      mx = fmaxf(mx, acc);
    }
    float sum = 0.f;
    for (int j = 0; j < KEEPT; j++) {
      float e = __expf(ssc[t][j] - mx);
      ssc[t][j] = e;
      sum += e;
    }
    float inv = 1.f / sum;
    float oa[64];
#pragma unroll
    for (int d = 0; d < 64; d++) oa[d] = 0.f;
    for (int j = 0; j < KEEPT; j++) {
      float w = ssc[t][j] * inv;
#pragma unroll
      for (int d = 0; d < 64; d++) oa[d] += w * vs[j][d];
    }
    __hip_bfloat16* orow = o + (size_t)(b * KEEPT + t) * DIMV + hh * 64;
#pragma unroll
    for (int d = 0; d < 64; d++) orow[d] = __float2bfloat16(oa[d]);
  }
}

// ---------------------------------------------------------------------------
extern "C" void kernel_launch(void* const* d_in, const int* in_sizes, int n_in,
                              void* d_out, int out_size, void* d_ws, size_t ws_size,
                              hipStream_t stream)
{
  (void)in_sizes; (void)n_in; (void)out_size;
  const float* inputs = (const float*)d_in[0];
  const float* conv_w = (const float*)d_in[1];
  const float* ct     = (const float*)d_in[2];
  const float* pe     = (const float*)d_in[3];
  const float* ln1_s  = (const float*)d_in[4];
  const float* ln1_b  = (const float*)d_in[5];
  const float* qkv_w  = (const float*)d_in[6];
  const float* proj_w = (const float*)d_in[7];
  const float* ln2_s  = (const float*)d_in[8];
  const float* ln2_b  = (const float*)d_in[9];
  const float* w1     = (const float*)d_in[10];
  const float* b1     = (const float*)d_in[11];
  const float* w2     = (const float*)d_in[12];
  const float* b2     = (const float*)d_in[13];
  const int*   mask   = (const int*)d_in[14];
  float* out = (float*)d_out;

  // workspace layout (bytes):
  //   x      fp32 MTOK*768          9,633,792
  //   h      bf16 MTOK*768          4,816,896   (also apix)
  //   big    bf16 max(qkv, g)      19,267,584   (qkv: MTOK*2304, g: MTOK*3072)
  //   convT  bf16 768*768           1,179,648
  //   wbuf   bf16 LSTRIDE [*12]    14,155,776 each
  char* wsb = (char*)d_ws;
  float*          x     = (float*)wsb;
  __hip_bfloat16* h     = (__hip_bfloat16*)(wsb + 9633792);
  __hip_bfloat16* big   = (__hip_bfloat16*)(wsb + 9633792 + 4816896);
  __hip_bfloat16* convT = (__hip_bfloat16*)(wsb + 9633792 + 4816896 + 19267584);
  __hip_bfloat16* wbuf  = (__hip_bfloat16*)(wsb + 9633792 + 4816896 + 19267584 + 1179648);
  const size_t base_bytes = 9633792ull + 4816896 + 19267584 + 1179648;
  const bool all_mode = ws_size >= base_bytes + 12ull * LSTRIDE * 2;

  __hip_bfloat16* apix = h;
  __hip_bfloat16* qkv  = big;
  __hip_bfloat16* g    = big;

  dim3 blk(256);
  const int nelem = MTOK * DIMV;
  const int nblk  = (nelem + 255) / 256;
  const int mg    = (MTOK + 127) / 128;   // 25

  transpose_one<<<576, blk, 0, stream>>>(conv_w, convT, 768, 768);
  if (all_mode)
    convert_weights<<<dim3(6912, 12), blk, 0, stream>>>(
        qkv_w, proj_w, w1, w2, wbuf, 0, LSTRIDE);

  gather_patches<<<nblk, blk, 0, stream>>>(inputs, mask, apix);
  gemm_mfma<64, EPI_NONE, false><<<dim3(12, mg), blk, 0, stream>>>(
      (const ushort*)apix, (const ushort*)convT, nullptr, nullptr, x,
      MTOK, DIMV, DIMV);
  finish_embed<<<nblk, blk, 0, stream>>>(x, ct, pe, mask);

  for (int l = 0; l < NDEPTH; l++) {
    __hip_bfloat16* wl = wbuf + (all_mode ? (size_t)l * LSTRIDE : 0);
    if (!all_mode)
      convert_weights<<<dim3(6912, 1), blk, 0, stream>>>(
          qkv_w, proj_w, w1, w2, wbuf, l, 0);
    const ushort* qkvT  = (const ushort*)wl;
    const ushort* projT = (const ushort*)(wl + QKV_TE);
    const ushort* w1T   = (const ushort*)(wl + QKV_TE + PROJ_TE);
    const ushort* w2T   = (const ushort*)(wl + QKV_TE + PROJ_TE + W1_TE);

    layernorm_k<<<MTOK, blk, 0, stream>>>(x, ln1_s + l * DIMV, ln1_b + l * DIMV, h);
    gemm_mfma<128, EPI_NONE, true><<<dim3(18, mg), blk, 0, stream>>>(
        (const ushort*)h, qkvT, nullptr, nullptr, qkv, MTOK, 3 * DIMV, DIMV);
    attn_k<<<dim3(BATCH, NHEADS), dim3(64), 0, stream>>>(qkv, h);
    gemm_mfma<64, EPI_RESID, false><<<dim3(12, mg), blk, 0, stream>>>(
        (const ushort*)h, projT, x, nullptr, x, MTOK, DIMV, DIMV);
    layernorm_k<<<MTOK, blk, 0, stream>>>(x, ln2_s + l * DIMV, ln2_b + l * DIMV, h);
    gemm_mfma<128, EPI_BIAS_GELU, true><<<dim3(24, mg), blk, 0, stream>>>(
        (const ushort*)h, w1T, nullptr, b1 + (size_t)l * FFV, g, MTOK, FFV, DIMV);
    float* dst = (l == NDEPTH - 1) ? out : x;
    gemm_mfma<64, EPI_BIAS_RESID, false><<<dim3(12, mg), blk, 0, stream>>>(
        (const ushort*)g, w2T, x, b2 + (size_t)l * DIMV, dst, MTOK, DIMV, FFV);
  }
}

// Round 3
// 2499.816 us; speedup vs baseline: 5.0224x; 1.0922x over previous
//
#include <hip/hip_runtime.h>
#include <hip/hip_bf16.h>
#include <math.h>

#define DIMV   768
#define BATCH  64
#define KEEPT  49
#define MTOK   (BATCH*KEEPT)   // 3136
#define NHEADS 12
#define DHEAD  64
#define FFV    3072
#define NDEPTH 12

typedef short short8 __attribute__((ext_vector_type(8)));
typedef float floatx4 __attribute__((ext_vector_type(4)));
typedef unsigned short ushort;

__device__ __forceinline__ ushort f2bf(float f) {
  __hip_bfloat16 h = __float2bfloat16(f);
  return *(ushort*)&h;
}

// ---------------------------------------------------------------------------
__device__ __forceinline__ void async_cp16(const void* g, void* l) {
  __builtin_amdgcn_global_load_lds((const __attribute__((address_space(1))) void*)g,
                                   (__attribute__((address_space(3))) void*)l,
                                   16, 0, 0);
}

// ---------------------------------------------------------------------------
// gather kept-patch pixels into (MTOK x 768) bf16 matrix
__global__ __launch_bounds__(256) void gather_patches(
    const float* __restrict__ inp, const int* __restrict__ mask,
    __hip_bfloat16* __restrict__ apix)
{
  int gid = blockIdx.x * 256 + threadIdx.x;
  if (gid >= MTOK * DIMV) return;
  int r = gid / DIMV, k = gid - r * DIMV;
  int b = r / KEEPT, t = r - b * KEEPT;
  int j = mask[t];
  j = j < 0 ? 0 : (j > 196 ? 196 : j);   // JAX clamps OOB gather indices
  float v = 0.f;
  if (j > 0) {
    int p  = j - 1, py = p / 14, px = p - py * 14;
    int ky = k / 48, rem = k - ky * 48, kx = rem / 3, c = rem - kx * 3;
    v = inp[(((b * 224) + py * 16 + ky) * 224 + px * 16 + kx) * 3 + c];
  }
  apix[gid] = __float2bfloat16(v);
}

// x = (j==0 ? ct : x) + pe[j]   (fp32 residual stream)
__global__ __launch_bounds__(256) void finish_embed(
    float* __restrict__ x, const float* __restrict__ ct,
    const float* __restrict__ pe, const int* __restrict__ mask)
{
  int gid = blockIdx.x * 256 + threadIdx.x;
  if (gid >= MTOK * DIMV) return;
  int r = gid / DIMV, d = gid - r * DIMV;
  int t = r % KEEPT;
  int j = mask[t];
  j = j < 0 ? 0 : (j > 196 ? 196 : j);
  float base = (j == 0) ? ct[d] : x[gid];
  x[gid] = base + pe[j * DIMV + d];
}

// ---------------------------------------------------------------------------
// row layernorm fp32 -> bf16, eps=1e-9
__global__ __launch_bounds__(256) void layernorm_k(
    const float* __restrict__ x, const float* __restrict__ sc,
    const float* __restrict__ bi, __hip_bfloat16* __restrict__ out)
{
  __shared__ float red[8];
  int r = blockIdx.x;
  const float* xr = x + (size_t)r * DIMV;
  int t = threadIdx.x;
  float v[3];
  float s = 0.f, ss = 0.f;
#pragma unroll
  for (int i = 0; i < 3; i++) {
    float a = xr[t + i * 256];
    v[i] = a; s += a; ss += a * a;
  }
#pragma unroll
  for (int off = 32; off > 0; off >>= 1) {
    s  += __shfl_down(s,  off, 64);
    ss += __shfl_down(ss, off, 64);
  }
  int wave = t >> 6, lane = t & 63;
  if (lane == 0) { red[wave] = s; red[4 + wave] = ss; }
  __syncthreads();
  if (t == 0) {
    float a  = red[0] + red[1] + red[2] + red[3];
    float b2 = red[4] + red[5] + red[6] + red[7];
    float m  = a * (1.f / DIMV);
    float var = b2 * (1.f / DIMV) - m * m;
    red[0] = m;
    red[1] = rsqrtf(var + 1e-9f);
  }
  __syncthreads();
  float m = red[0], rs = red[1];
  __hip_bfloat16* outr = out + (size_t)r * DIMV;
#pragma unroll
  for (int i = 0; i < 3; i++) {
    int d = t + i * 256;
    outr[d] = __float2bfloat16((v[i] - m) * rs * sc[d] + bi[d]);
  }
}

// ---------------------------------------------------------------------------
// 64x64-tile fp32 -> bf16 transpose (dst[c][r] = bf16(src[r][c])), vectorized:
// float4 reads, ushort4 (8B) bf16 writes through a 64x65 fp32 LDS tile.
__device__ __forceinline__ void transpose_tile64(
    const float* __restrict__ src, __hip_bfloat16* __restrict__ dst,
    int R, int C, int tr, int tcc)
{
  __shared__ float lds[64][65];
  const int tid = threadIdx.x;
  const int r0 = tr * 64, c0 = tcc * 64;
  const int lr = tid >> 4, lc4 = (tid & 15) * 4;
#pragma unroll
  for (int p = 0; p < 4; p++) {
    float4 v = *(const float4*)(src + (size_t)(r0 + p * 16 + lr) * C + c0 + lc4);
    lds[p * 16 + lr][lc4 + 0] = v.x;
    lds[p * 16 + lr][lc4 + 1] = v.y;
    lds[p * 16 + lr][lc4 + 2] = v.z;
    lds[p * 16 + lr][lc4 + 3] = v.w;
  }
  __syncthreads();
#pragma unroll
  for (int p = 0; p < 4; p++) {
    int c  = p * 16 + (tid >> 4);
    int rc = (tid & 15) * 4;
    ushort4 ov;
    ov.x = f2bf(lds[rc + 0][c]);
    ov.y = f2bf(lds[rc + 1][c]);
    ov.z = f2bf(lds[rc + 2][c]);
    ov.w = f2bf(lds[rc + 3][c]);
    *(ushort4*)((ushort*)dst + (size_t)(c0 + c) * R + r0 + rc) = ov;
  }
}

__global__ __launch_bounds__(256) void transpose_one(
    const float* __restrict__ src, __hip_bfloat16* __restrict__ dst, int R, int C)
{
  int tc = C >> 6;
  transpose_tile64(src, dst, R, C, blockIdx.x / tc, blockIdx.x % tc);
}

// fused per-layer weight convert+transpose (64x64 tiles).
// tiles: qkv(768x2304)=432, proj(768x768)=144, w1(768x3072)=576, w2(3072x768)=576
#define QKV_TE  ((size_t)2304*768)
#define PROJ_TE ((size_t)768*768)
#define W1_TE   ((size_t)3072*768)
#define W2_TE   ((size_t)768*3072)
#define LSTRIDE (QKV_TE + PROJ_TE + W1_TE + W2_TE)   // 7,077,888 elems

__global__ __launch_bounds__(256) void convert_weights(
    const float* __restrict__ qkv_w, const float* __restrict__ proj_w,
    const float* __restrict__ w1, const float* __restrict__ w2,
    __hip_bfloat16* __restrict__ dstBase, int layer0, size_t dstStride)
{
  int l = layer0 + blockIdx.y;
  __hip_bfloat16* d = dstBase + (size_t)blockIdx.y * dstStride;
  int tile = blockIdx.x;
  const float* src; __hip_bfloat16* dst; int R, C, t0;
  if (tile < 432)       { src = qkv_w  + (size_t)l*768*2304; dst = d;                          R=768;  C=2304; t0=tile; }
  else if (tile < 576)  { src = proj_w + (size_t)l*768*768;  dst = d + QKV_TE;                 R=768;  C=768;  t0=tile-432; }
  else if (tile < 1152) { src = w1     + (size_t)l*768*3072; dst = d + QKV_TE+PROJ_TE;         R=768;  C=3072; t0=tile-576; }
  else                  { src = w2     + (size_t)l*3072*768; dst = d + QKV_TE+PROJ_TE+W1_TE;   R=3072; C=768;  t0=tile-1152; }
  int tc = C >> 6;
  transpose_tile64(src, dst, R, C, t0 / tc, t0 % tc);
}

// ---------------------------------------------------------------------------
// bf16 MFMA GEMM: C = A(MxK) * Bt^T  (Bt is N x K row-major, pre-transposed)
// block tile 128 x TN, 4 waves, 16x16x32 MFMA, fp32 accum.
enum { EPI_NONE = 0, EPI_RESID = 1, EPI_BIAS_GELU = 2, EPI_BIAS_RESID = 3 };

template <int TN, int EPI, bool OUT_BF16>
__global__ __launch_bounds__(256) void gemm_mfma(
    const ushort* __restrict__ A, const ushort* __restrict__ Bt,
    const float* __restrict__ Cin, const float* __restrict__ bias,
    void* __restrict__ Cout, int M, int N, int K)
{
  constexpr int AM = (TN == 128) ? 4 : 2;   // A frags / wave (WM = AM*16)
  constexpr int B_LOADS = TN / 64;          // 1KB wave-loads for Bs
  __shared__ ushort As[128 * 32];
  __shared__ ushort Bs[TN * 32];

  const int tid  = threadIdx.x;
  const int wave = tid >> 6, lane = tid & 63;
  const int bm = blockIdx.y, bn = blockIdx.x;

  const int wm0 = (TN == 128) ? (wave & 1) * 64 : wave * 32;
  const int wn0 = (TN == 128) ? (wave >> 1) * 64 : 0;

  floatx4 acc[AM][4];
#pragma unroll
  for (int i = 0; i < AM; i++)
#pragma unroll
    for (int j = 0; j < 4; j++) { floatx4 z = {0.f,0.f,0.f,0.f}; acc[i][j] = z; }

  // staging source pointers: lane -> row (lane>>2), k-chunk (lane&3)*8
  const int lrow = lane >> 2, lchunk = (lane & 3) * 8;
  const ushort* aSrc[2];
  ushort*       aDst[2];
#pragma unroll
  for (int i = 0; i < 2; i++) {
    int row = bm * 128 + (wave * 2 + i) * 16 + lrow;
    row = row < M - 1 ? row : M - 1;
    aSrc[i] = A + (size_t)row * K + lchunk;
    aDst[i] = As + (wave * 2 + i) * 512;      // wave-uniform base (1KB per load)
  }
  const ushort* bSrc[B_LOADS];
  ushort*       bDst[B_LOADS];
#pragma unroll
  for (int i = 0; i < B_LOADS; i++) {
    int row = bn * TN + (wave * B_LOADS + i) * 16 + lrow;
    bSrc[i] = Bt + (size_t)row * K + lchunk;
    bDst[i] = Bs + (wave * B_LOADS + i) * 512;
  }

  for (int k0 = 0; k0 < K; k0 += 32) {
    __syncthreads();
#pragma unroll
    for (int i = 0; i < 2; i++)       async_cp16(aSrc[i] + k0, aDst[i]);
#pragma unroll
    for (int i = 0; i < B_LOADS; i++) async_cp16(bSrc[i] + k0, bDst[i]);
    __syncthreads();

    short8 af[AM], bf[4];
#pragma unroll
    for (int mt = 0; mt < AM; mt++)
      af[mt] = *(const short8*)&As[(wm0 + mt * 16 + (lane & 15)) * 32 + (lane >> 4) * 8];
#pragma unroll
    for (int nt = 0; nt < 4; nt++)
      bf[nt] = *(const short8*)&Bs[(wn0 + nt * 16 + (lane & 15)) * 32 + (lane >> 4) * 8];
#pragma unroll
    for (int mt = 0; mt < AM; mt++)
#pragma unroll
      for (int nt = 0; nt < 4; nt++)
        acc[mt][nt] = __builtin_amdgcn_mfma_f32_16x16x32_bf16(af[mt], bf[nt], acc[mt][nt], 0, 0, 0);
  }

  // epilogue: C row = wm0+mt*16+(lane>>4)*4+r, col = wn0+nt*16+(lane&15)
  const int colb = bn * TN + wn0 + (lane & 15);
  const int rq   = (lane >> 4) * 4;
#pragma unroll
  for (int mt = 0; mt < AM; mt++) {
#pragma unroll
    for (int r = 0; r < 4; r++) {
      int row = bm * 128 + wm0 + mt * 16 + rq + r;
      if (row >= M) continue;
#pragma unroll
      for (int nt = 0; nt < 4; nt++) {
        int col = colb + nt * 16;
        float u = acc[mt][nt][r];
        if (EPI == EPI_BIAS_GELU || EPI == EPI_BIAS_RESID) u += bias[col];
        if (EPI == EPI_BIAS_GELU) {
          float t3 = u * u * u;
          u = 0.5f * u * (1.f + tanhf(0.7978845608028654f * (u + 0.044715f * t3)));
        }
        if (EPI == EPI_RESID || EPI == EPI_BIAS_RESID) u += Cin[(size_t)row * N + col];
        if (OUT_BF16)
          ((__hip_bfloat16*)Cout)[(size_t)row * N + col] = __float2bfloat16(u);
        else
          ((float*)Cout)[(size_t)row * N + col] = u;
      }
    }
  }
}

// ---------------------------------------------------------------------------
// MFMA fused attention: one block (1 wave) per (batch, head).
// QK^T -> masked softmax (in-register, shfl over 16-lane frag groups) -> PV.
// LDS rows padded to 72 elems (144B: 16B-aligned, conflict-light b128 reads).
__global__ __launch_bounds__(64) void attn_mfma(
    const ushort* __restrict__ qkv, ushort* __restrict__ o)
{
  __shared__ ushort qA[64 * 72];   // Q rows (token, d)
  __shared__ ushort kB[64 * 72];   // K rows (token, d)
  __shared__ ushort vT[64 * 72];   // V^T rows (d, token)
  __shared__ ushort pA[64 * 72];   // P rows (q-token, k-token), bf16
  const int b = blockIdx.x, hh = blockIdx.y;
  const int lane = threadIdx.x;
  const int fr = lane & 15, fc = lane >> 4;

  const ushort* base = qkv + (size_t)b * KEEPT * (3 * DIMV) + hh * 64;
  for (int r = 0; r < KEEPT; r++) {
    const ushort* row = base + (size_t)r * (3 * DIMV);
    qA[r * 72 + lane] = row[lane];
    kB[r * 72 + lane] = row[DIMV + lane];
    vT[lane * 72 + r] = row[2 * DIMV + lane];
  }
#pragma unroll
  for (int r = KEEPT; r < 64; r++) {
    qA[r * 72 + lane] = 0;
    kB[r * 72 + lane] = 0;
    vT[lane * 72 + r] = 0;
  }
  __syncthreads();

  floatx4 sacc[4][4];
#pragma unroll
  for (int mt = 0; mt < 4; mt++)
#pragma unroll
    for (int nt = 0; nt < 4; nt++) { floatx4 z = {0.f,0.f,0.f,0.f}; sacc[mt][nt] = z; }

#pragma unroll
  for (int kk = 0; kk < 2; kk++) {
    const int ch = kk * 32 + fc * 8;
    short8 af[4], bf[4];
#pragma unroll
    for (int mt = 0; mt < 4; mt++) af[mt] = *(const short8*)&qA[(mt * 16 + fr) * 72 + ch];
#pragma unroll
    for (int nt = 0; nt < 4; nt++) bf[nt] = *(const short8*)&kB[(nt * 16 + fr) * 72 + ch];
#pragma unroll
    for (int mt = 0; mt < 4; mt++)
#pragma unroll
      for (int nt = 0; nt < 4; nt++)
        sacc[mt][nt] = __builtin_amdgcn_mfma_f32_16x16x32_bf16(af[mt], bf[nt], sacc[mt][nt], 0, 0, 0);
  }

  // scale, mask cols j>=49, softmax per q-row (row lives in 16 lanes x 4 nt-regs)
  float inv[4][4];
#pragma unroll
  for (int mt = 0; mt < 4; mt++) {
#pragma unroll
    for (int r = 0; r < 4; r++) {
      float mx = -1e30f;
#pragma unroll
      for (int nt = 0; nt < 4; nt++) {
        float s = sacc[mt][nt][r] * 0.125f;        // 1/sqrt(64)
        if (nt == 3 && fr >= 1) s = -1e30f;        // j = 48+fr >= 49
        sacc[mt][nt][r] = s;
        mx = fmaxf(mx, s);
      }
      mx = fmaxf(mx, __shfl_xor(mx, 1, 64));
      mx = fmaxf(mx, __shfl_xor(mx, 2, 64));
      mx = fmaxf(mx, __shfl_xor(mx, 4, 64));
      mx = fmaxf(mx, __shfl_xor(mx, 8, 64));
      float sum = 0.f;
#pragma unroll
      for (int nt = 0; nt < 4; nt++) {
        float e = __expf(sacc[mt][nt][r] - mx);
        sacc[mt][nt][r] = e;
        sum += e;
      }
      sum += __shfl_xor(sum, 1, 64);
      sum += __shfl_xor(sum, 2, 64);
      sum += __shfl_xor(sum, 4, 64);
      sum += __shfl_xor(sum, 8, 64);
      inv[mt][r] = 1.f / sum;
    }
  }

  // P (unnormalized) -> LDS in A-operand (row-major) layout, bf16
#pragma unroll
  for (int mt = 0; mt < 4; mt++)
#pragma unroll
    for (int r = 0; r < 4; r++)
#pragma unroll
      for (int nt = 0; nt < 4; nt++)
        pA[(mt * 16 + fc * 4 + r) * 72 + nt * 16 + fr] = f2bf(sacc[mt][nt][r]);
  __syncthreads();

  floatx4 oacc[4][4];
#pragma unroll
  for (int mt = 0; mt < 4; mt++)
#pragma unroll
    for (int nt = 0; nt < 4; nt++) { floatx4 z = {0.f,0.f,0.f,0.f}; oacc[mt][nt] = z; }

#pragma unroll
  for (int kk = 0; kk < 2; kk++) {
    const int ch = kk * 32 + fc * 8;
    short8 af[4], bf[4];
#pragma unroll
    for (int mt = 0; mt < 4; mt++) af[mt] = *(const short8*)&pA[(mt * 16 + fr) * 72 + ch];
#pragma unroll
    for (int nt = 0; nt < 4; nt++) bf[nt] = *(const short8*)&vT[(nt * 16 + fr) * 72 + ch];
#pragma unroll
    for (int mt = 0; mt < 4; mt++)
#pragma unroll
      for (int nt = 0; nt < 4; nt++)
        oacc[mt][nt] = __builtin_amdgcn_mfma_f32_16x16x32_bf16(af[mt], bf[nt], oacc[mt][nt], 0, 0, 0);
  }

  ushort* obase = o + (size_t)b * KEEPT * DIMV + hh * 64;
#pragma unroll
  for (int mt = 0; mt < 4; mt++)
#pragma unroll
    for (int r = 0; r < 4; r++) {
      int q = mt * 16 + fc * 4 + r;
      if (q < KEEPT) {
#pragma unroll
        for (int nt = 0; nt < 4; nt++)
          obase[(size_t)q * DIMV + nt * 16 + fr] = f2bf(oacc[mt][nt][r] * inv[mt][r]);
      }
    }
}

// ---------------------------------------------------------------------------
extern "C" void kernel_launch(void* const* d_in, const int* in_sizes, int n_in,
                              void* d_out, int out_size, void* d_ws, size_t ws_size,
                              hipStream_t stream)
{
  (void)in_sizes; (void)n_in; (void)out_size;
  const float* inputs = (const float*)d_in[0];
  const float* conv_w = (const float*)d_in[1];
  const float* ct     = (const float*)d_in[2];
  const float* pe     = (const float*)d_in[3];
  const float* ln1_s  = (const float*)d_in[4];
  const float* ln1_b  = (const float*)d_in[5];
  const float* qkv_w  = (const float*)d_in[6];
  const float* proj_w = (const float*)d_in[7];
  const float* ln2_s  = (const float*)d_in[8];
  const float* ln2_b  = (const float*)d_in[9];
  const float* w1     = (const float*)d_in[10];
  const float* b1     = (const float*)d_in[11];
  const float* w2     = (const float*)d_in[12];
  const float* b2     = (const float*)d_in[13];
  const int*   mask   = (const int*)d_in[14];
  float* out = (float*)d_out;

  // workspace layout (bytes):
  //   x      fp32 MTOK*768          9,633,792
  //   h      bf16 MTOK*768          4,816,896   (also apix)
  //   big    bf16 max(qkv, g)      19,267,584   (qkv: MTOK*2304, g: MTOK*3072)
  //   convT  bf16 768*768           1,179,648
  //   wbuf   bf16 LSTRIDE [*12]    14,155,776 each
  char* wsb = (char*)d_ws;
  float*          x     = (float*)wsb;
  __hip_bfloat16* h     = (__hip_bfloat16*)(wsb + 9633792);
  __hip_bfloat16* big   = (__hip_bfloat16*)(wsb + 9633792 + 4816896);
  __hip_bfloat16* convT = (__hip_bfloat16*)(wsb + 9633792 + 4816896 + 19267584);
  __hip_bfloat16* wbuf  = (__hip_bfloat16*)(wsb + 9633792 + 4816896 + 19267584 + 1179648);
  const size_t base_bytes = 9633792ull + 4816896 + 19267584 + 1179648;
  const bool all_mode = ws_size >= base_bytes + 12ull * LSTRIDE * 2;

  __hip_bfloat16* apix = h;
  __hip_bfloat16* qkv  = big;
  __hip_bfloat16* g    = big;

  dim3 blk(256);
  const int nelem = MTOK * DIMV;
  const int nblk  = (nelem + 255) / 256;
  const int mg    = (MTOK + 127) / 128;   // 25

  transpose_one<<<144, blk, 0, stream>>>(conv_w, convT, 768, 768);
  if (all_mode)
    convert_weights<<<dim3(1728, 12), blk, 0, stream>>>(
        qkv_w, proj_w, w1, w2, wbuf, 0, LSTRIDE);

  gather_patches<<<nblk, blk, 0, stream>>>(inputs, mask, apix);
  gemm_mfma<64, EPI_NONE, false><<<dim3(12, mg), blk, 0, stream>>>(
      (const ushort*)apix, (const ushort*)convT, nullptr, nullptr, x,
      MTOK, DIMV, DIMV);
  finish_embed<<<nblk, blk, 0, stream>>>(x, ct, pe, mask);

  for (int l = 0; l < NDEPTH; l++) {
    __hip_bfloat16* wl = wbuf + (all_mode ? (size_t)l * LSTRIDE : 0);
    if (!all_mode)
      convert_weights<<<dim3(1728, 1), blk, 0, stream>>>(
          qkv_w, proj_w, w1, w2, wbuf, l, 0);
    const ushort* qkvT  = (const ushort*)wl;
    const ushort* projT = (const ushort*)(wl + QKV_TE);
    const ushort* w1T   = (const ushort*)(wl + QKV_TE + PROJ_TE);
    const ushort* w2T   = (const ushort*)(wl + QKV_TE + PROJ_TE + W1_TE);

    layernorm_k<<<MTOK, blk, 0, stream>>>(x, ln1_s + l * DIMV, ln1_b + l * DIMV, h);
    gemm_mfma<128, EPI_NONE, true><<<dim3(18, mg), blk, 0, stream>>>(
        (const ushort*)h, qkvT, nullptr, nullptr, qkv, MTOK, 3 * DIMV, DIMV);
    attn_mfma<<<dim3(BATCH, NHEADS), dim3(64), 0, stream>>>(
        (const ushort*)qkv, (ushort*)h);
    gemm_mfma<64, EPI_RESID, false><<<dim3(12, mg), blk, 0, stream>>>(
        (const ushort*)h, projT, x, nullptr, x, MTOK, DIMV, DIMV);
    layernorm_k<<<MTOK, blk, 0, stream>>>(x, ln2_s + l * DIMV, ln2_b + l * DIMV, h);
    gemm_mfma<128, EPI_BIAS_GELU, true><<<dim3(24, mg), blk, 0, stream>>>(
        (const ushort*)h, w1T, nullptr, b1 + (size_t)l * FFV, g, MTOK, FFV, DIMV);
    float* dst = (l == NDEPTH - 1) ? out : x;
    gemm_mfma<64, EPI_BIAS_RESID, false><<<dim3(12, mg), blk, 0, stream>>>(
        (const ushort*)g, w2T, x, b2 + (size_t)l * DIMV, dst, MTOK, DIMV, FFV);
  }
}